// Round 9
// baseline (107.006 us; speedup 1.0000x reference)
//
#include <hip/hip_runtime.h>

// FOFE windowed encoder — sweep-ordered + register-rolling rows.
// out[b,c,i,t] = z[t-1] - alpha^{w_i} * z[t-1-w_i];  z[t]=alpha*z[t-1]+x[t]
// w_i = i (i<48), w_48 = 64. out (8,512,49,513) f32 (~412 MB).
//
// R6 (sweep, 8-LDS-read rows) = 85.9us; R7 (+decode) = 100.3 -> inner-loop
// weight IS on the critical path at 1 block/CU. Here: per output row a wave
// does 1 LDS read + 4 fmaf + 1 16B store, rolling out_{j+1} = out_j +
// alpha^j x[t-1-j] in registers down a 12-row band (band head initialized
// directly from z). Sweep skeleton kept: 256 blocks, slabs g = tau*256+blk.
// No per-tau barriers (LDS read-only after phase 1) -> no store-queue drains.

#define CC 512
#define LL 512
#define NW 49
#define LO 513
#define SLAB (NW * LO)        // 25137 floats per (b,c)
#define GRID 256
#define NTAU 16
#define ZOFF 65               // z[q] at ZOFF+q; zeros for q<0 (idx 0..64)
#define ZROW 640
#define XPAD 48               // x[m] at XPAD+m; zeros m<0 (need m >= -48)
#define XROW 560

typedef float f32x4 __attribute__((ext_vector_type(4)));

// XOR-swizzle for stride-4 lane access: 2 lanes/bank (free, m136).
__device__ __forceinline__ int swz(int i) { return i ^ ((i >> 5) & 3); }

__global__ __launch_bounds__(512)
void fofe_kernel(const float* __restrict__ x,
                 const float* __restrict__ alpha,
                 float* __restrict__ out)
{
    __shared__ float zs[NTAU][ZROW];   // 40 KB
    __shared__ float xs[NTAU][XROW];   // 35 KB

    const int tid  = threadIdx.x;
    const int wid  = tid >> 6;         // 0..7
    const int lane = tid & 63;
    const int blk  = blockIdx.x;

    // ---------- phase 1: scan + stage z and x for all 16 slabs ----------
    for (int tau = wid; tau < NTAU; tau += 8) {
        const int g = tau * GRID + blk;
        const float al = alpha[g & (CC - 1)];
        const float* xr = x + (size_t)g * LL;

        const f32x4 xv0 = reinterpret_cast<const f32x4*>(xr)[lane * 2];
        const f32x4 xv1 = reinterpret_cast<const f32x4*>(xr)[lane * 2 + 1];
        const float xe[8] = {xv0.x, xv0.y, xv0.z, xv0.w,
                             xv1.x, xv1.y, xv1.z, xv1.w};
        float l[8];
        {
            float s = 0.f;
            #pragma unroll
            for (int m = 0; m < 8; ++m) { s = fmaf(al, s, xe[m]); l[m] = s; }
        }
        float pw[8];                   // alpha^{m+1}
        {
            float p = al;
            #pragma unroll
            for (int m = 0; m < 8; ++m) { pw[m] = p; p *= al; }
        }
        float A = pw[7], S = l[7];
        #pragma unroll
        for (int off = 1; off < 64; off <<= 1) {
            const float Ap = __shfl_up(A, off);
            const float Sp = __shfl_up(S, off);
            if (lane >= off) { S = fmaf(A, Sp, S); A = A * Ap; }
        }
        float carry = __shfl_up(S, 1);
        if (lane == 0) carry = 0.f;

        float* z  = zs[tau];
        float* xw = xs[tau];
        z[swz(lane)] = 0.f;                       // z idx 0..63
        if (lane == 0) z[swz(64)] = 0.f;          // z[-1]
        if (lane < XPAD) xw[swz(lane)] = 0.f;     // x front zeros
        #pragma unroll
        for (int m = 0; m < 8; ++m) {
            z[swz(ZOFF + lane * 8 + m)] = fmaf(pw[m], carry, l[m]);
            xw[swz(XPAD + lane * 8 + m)] = xe[m];
        }
    }
    __syncthreads();   // only barrier: LDS is read-only below

    // ---------- phase 2: sweep slabs; rolling 12-row bands ----------
    const int rg   = wid >> 1;              // row band: rows 12*rg .. 12*rg+11
    const int half = wid & 1;               // cols: h0 -> [0,256), h1 -> [257,513)
    const int t0   = half * 257 + 4 * lane;
    const int j0   = 12 * rg;

    for (int tau = 0; tau < NTAU; ++tau) {
        const int g = tau * GRID + blk;
        const float al = alpha[g & (CC - 1)];
        const float* z  = zs[tau];
        const float* xw = xs[tau];
        float* oslab = out + (size_t)g * SLAB;

        // p = alpha^j0 (j0 <= 36, 6-bit ladder)
        float p = 1.f;
        {
            float m = al;
            #pragma unroll
            for (int b = 0; b < 6; ++b) { if (j0 & (1 << b)) p *= m; m *= m; }
        }

        // band-head init: out_{j0}[t] = z[t-1] - alpha^{j0} z[t-1-j0]
        const int kb = ZOFF - 1 + t0;
        f32x4 acc;
        acc.x = fmaf(-p, z[swz(kb     - j0)], z[swz(kb    )]);
        acc.y = fmaf(-p, z[swz(kb + 1 - j0)], z[swz(kb + 1)]);
        acc.z = fmaf(-p, z[swz(kb + 2 - j0)], z[swz(kb + 2)]);
        acc.w = fmaf(-p, z[swz(kb + 3 - j0)], z[swz(kb + 3)]);

        // x sliding window: w0..w3 = x[t0-1-j0 .. t0+2-j0]
        const int xb = XPAD + t0 - 1 - j0;
        float w0 = xw[swz(xb)];
        float w1 = xw[swz(xb + 1)];
        float w2 = xw[swz(xb + 2)];
        float w3 = xw[swz(xb + 3)];

        float* op = oslab + j0 * LO + t0;
        #pragma unroll
        for (int s = 0; s < 12; ++s) {
            f32x4 tv = acc;
            __builtin_memcpy(op, &tv, 16);       // 4B-aligned 16B store
            op += LO;
            if (s < 11) {
                const float nw = xw[swz(xb - 1 - s)];
                acc.x = fmaf(p, w0, acc.x);
                acc.y = fmaf(p, w1, acc.y);
                acc.z = fmaf(p, w2, acc.z);
                acc.w = fmaf(p, w3, acc.w);
                w3 = w2; w2 = w1; w1 = w0; w0 = nw;
                p *= al;
            }
        }

        // row 48 (w = 64): direct from z; waves rg==1
        if (rg == 1) {
            float a64 = al;
            #pragma unroll
            for (int b = 0; b < 6; ++b) a64 *= a64;   // al^64
            f32x4 v;
            v.x = fmaf(-a64, z[swz(kb     - 64)], z[swz(kb    )]);
            v.y = fmaf(-a64, z[swz(kb + 1 - 64)], z[swz(kb + 1)]);
            v.z = fmaf(-a64, z[swz(kb + 2 - 64)], z[swz(kb + 2)]);
            v.w = fmaf(-a64, z[swz(kb + 3 - 64)], z[swz(kb + 3)]);
            __builtin_memcpy(oslab + 48 * LO + t0, &v, 16);
        }

        // column t = 256: wave 0 shuffle-scan (proven in R4)
        if (wid == 0) {
            float pl = 1.f, mm = al;              // pl = alpha^lane
            #pragma unroll
            for (int b = 0; b < 6; ++b) { if (lane & (1 << b)) pl *= mm; mm *= mm; }
            float s = pl * xw[swz(XPAD + 255 - lane)];
            #pragma unroll
            for (int off = 1; off < 64; off <<= 1) {
                const float v = __shfl_up(s, off);
                if (lane >= off) s += v;
            }
            float* ocol = oslab + 256;
            if (lane <= 46) ocol[(lane + 1) * LO] = s;   // rows 1..47
            if (lane == 47) ocol[0] = 0.f;               // row 0
            if (lane == 63) ocol[48 * LO] = s;           // row 48 (w=64)
        }
    }
}

extern "C" void kernel_launch(void* const* d_in, const int* in_sizes, int n_in,
                              void* d_out, int out_size, void* d_ws, size_t ws_size,
                              hipStream_t stream)
{
    const float* x     = (const float*)d_in[0];
    const float* alpha = (const float*)d_in[1];
    float* out = (float*)d_out;

    fofe_kernel<<<GRID, 512, 0, stream>>>(x, alpha, out);
}

// Round 10
// 99.305 us; speedup vs baseline: 1.0776x; 1.0776x over previous
//
#include <hip/hip_runtime.h>

// FOFE windowed encoder — sweep-ordered, balanced row-per-wave, barrier-free.
// out[b,c,i,t] = z[t-1] - alpha^{w_i} * z[t-1-w_i];  z[t]=alpha*z[t-1]+x[t]
// w_i = i (i<48), w_48 = 64. out (8,512,49,513) f32 (~412 MB).
//
// R6 (sweep + row-per-wave + per-tau barrier) = 85.9 us, best. Its one clean
// defect: wave 0 owns 7 rows/tau vs 6 for waves 1-7 -> every barrier phase
// runs at wave 0's pace (~14% idle), + 16 store-queue drains.
// Fix ONLY that: flatten (tau,i) -> R = tau*49 + i; wave w takes R = w+8k
// (98 rows each, exactly balanced). tau = R/49 is monotone per wave -> sweep
// window stays tight with NO barrier (equal work/row => natural lockstep).
// Inner loop + store alignment byte-identical to R6. alpha^w via LDS LUT.

#define CC 512
#define LL 512
#define NW 49
#define LO 513
#define SLAB (NW * LO)        // 25137 floats per (b,c)
#define GRID 256
#define NTAU 16               // 4096 slabs / 256 blocks
#define NROWS (NTAU * NW)     // 784 rows per block
#define ZOFF 65               // z[q] at k = ZOFF + q; zeros for k < 65
#define ZROW 640

typedef float f32x4 __attribute__((ext_vector_type(4)));

// XOR-swizzle for stride-4 lane access: inject idx bits [6:5] into bank bits
// [1:0] -> 2 lanes/bank (free, m136). Involution, bijective on [0,640).
__device__ __forceinline__ int swz(int i) { return i ^ ((i >> 5) & 3); }

__global__ __launch_bounds__(512)
void fofe_kernel(const float* __restrict__ x,
                 const float* __restrict__ alpha,
                 float* __restrict__ out)
{
    __shared__ float zs[NTAU][ZROW];    // 40 KB
    __shared__ float lut[NTAU][NW];     // alpha^{w_i} per slab, 3.1 KB

    const int tid  = threadIdx.x;
    const int wid  = tid >> 6;          // 0..7
    const int lane = tid & 63;
    const int blk  = blockIdx.x;

    // ---------- phase 1: all 16 row-scans (wave w: tau = w, w+8) ----------
    for (int tau = wid; tau < NTAU; tau += 8) {
        const int g = tau * GRID + blk;
        const float al = alpha[g & (CC - 1)];
        const float* xr = x + (size_t)g * LL;

        const f32x4 xv0 = reinterpret_cast<const f32x4*>(xr)[lane * 2];
        const f32x4 xv1 = reinterpret_cast<const f32x4*>(xr)[lane * 2 + 1];
        const float xe[8] = {xv0.x, xv0.y, xv0.z, xv0.w,
                             xv1.x, xv1.y, xv1.z, xv1.w};
        float l[8];
        {
            float s = 0.f;
            #pragma unroll
            for (int m = 0; m < 8; ++m) { s = fmaf(al, s, xe[m]); l[m] = s; }
        }
        float pw[8];                    // alpha^{m+1}
        {
            float p = al;
            #pragma unroll
            for (int m = 0; m < 8; ++m) { pw[m] = p; p *= al; }
        }
        float A = pw[7], S = l[7];
        #pragma unroll
        for (int off = 1; off < 64; off <<= 1) {
            const float Ap = __shfl_up(A, off);
            const float Sp = __shfl_up(S, off);
            if (lane >= off) { S = fmaf(A, Sp, S); A = A * Ap; }
        }
        float carry = __shfl_up(S, 1);
        if (lane == 0) carry = 0.f;

        float* z = zs[tau];
        z[swz(lane)] = 0.f;             // k = 0..63
        if (lane == 0) z[swz(64)] = 0.f;// k = 64 (z[-1])
        #pragma unroll
        for (int m = 0; m < 8; ++m)
            z[swz(ZOFF + lane * 8 + m)] = fmaf(pw[m], carry, l[m]);
    }
    // alpha^w LUT (49 threads x 16 taus; one-time)
    if (tid < NW) {
        const int w = (tid < 48) ? tid : 64;
        for (int tau = 0; tau < NTAU; ++tau) {
            const int g = tau * GRID + blk;
            const float al = alpha[g & (CC - 1)];
            float p = 1.f, m = al;
            #pragma unroll
            for (int b = 0; b < 7; ++b) { if (w & (1 << b)) p *= m; m *= m; }
            lut[tau][tid] = p;
        }
    }
    __syncthreads();   // the only barrier; LDS is read-only below

    // ---------- phase 2: balanced barrier-free sweep, 98 rows per wave ------
    for (int R = wid; R < NROWS; R += 8) {
        const unsigned tau = (unsigned)R / NW;     // magic-mul divide
        const int      i   = R - (int)tau * NW;
        const int      g   = (int)tau * GRID + blk;
        const float*   z   = zs[tau];
        const int      w   = (i < 48) ? i : 64;
        const float    apw = lut[tau][i];
        float* op = out + (size_t)g * SLAB + i * LO;

        // element phase of op = (g*25137 + i*513) & 3 = (g + i) & 3
        const int peel = (4 - ((g + i) & 3)) & 3;
        const int k0b  = ZOFF - 1;                 // + t gives z[t-1]

        if (lane < peel)
            op[lane] = fmaf(-apw, z[swz(k0b + lane - w)], z[swz(k0b + lane)]);

        const int nf4  = (LO - peel) >> 2;         // 127 or 128
        const int tail = (LO - peel) & 3;
        for (int f = lane; f < nf4; f += 64) {
            const int t0 = peel + 4 * f;
            const int k0 = k0b + t0;
            f32x4 v;
            v.x = fmaf(-apw, z[swz(k0     - w)], z[swz(k0    )]);
            v.y = fmaf(-apw, z[swz(k0 + 1 - w)], z[swz(k0 + 1)]);
            v.z = fmaf(-apw, z[swz(k0 + 2 - w)], z[swz(k0 + 2)]);
            v.w = fmaf(-apw, z[swz(k0 + 3 - w)], z[swz(k0 + 3)]);
            *reinterpret_cast<f32x4*>(op + t0) = v;    // 16B-aligned
        }
        if (lane < tail) {
            const int t = peel + 4 * nf4 + lane;
            op[t] = fmaf(-apw, z[swz(k0b + t - w)], z[swz(k0b + t)]);
        }
    }
}

extern "C" void kernel_launch(void* const* d_in, const int* in_sizes, int n_in,
                              void* d_out, int out_size, void* d_ws, size_t ws_size,
                              hipStream_t stream)
{
    const float* x     = (const float*)d_in[0];
    const float* alpha = (const float*)d_in[1];
    float* out = (float*)d_out;

    fofe_kernel<<<GRID, 512, 0, stream>>>(x, alpha, out);
}

// Round 11
// 98.812 us; speedup vs baseline: 1.0829x; 1.0050x over previous
//
#include <hip/hip_runtime.h>

// FOFE windowed encoder — sweep-ordered, balanced row-per-wave, barrier-free.
// out[b,c,i,t] = z[t-1] - alpha^{w_i} * z[t-1-w_i];  z[t]=alpha*z[t-1]+x[t]
// w_i = i (i<48), w_48 = 64. out (8,512,49,513) f32 (~412 MB).
//
// R6 (sweep + row-per-wave + per-tau barrier) = 85.9 us, best. Its one clean
// defect: wave 0 owns 7 rows/tau vs 6 for waves 1-7 -> every barrier phase
// runs at wave 0's pace (~14% idle), + 16 store-queue drains.
// Fix ONLY that: flatten (tau,i) -> R = tau*49 + i; wave w takes R = w+8k
// (98 rows each, exactly balanced). tau = R/49 is monotone per wave -> sweep
// window stays tight with NO barrier (equal work/row => natural lockstep).
// Inner loop + store alignment byte-identical to R6. alpha^w via LDS LUT.

#define CC 512
#define LL 512
#define NW 49
#define LO 513
#define SLAB (NW * LO)        // 25137 floats per (b,c)
#define GRID 256
#define NTAU 16               // 4096 slabs / 256 blocks
#define NROWS (NTAU * NW)     // 784 rows per block
#define ZOFF 65               // z[q] at k = ZOFF + q; zeros for k < 65
#define ZROW 640

typedef float f32x4 __attribute__((ext_vector_type(4)));

// XOR-swizzle for stride-4 lane access: inject idx bits [6:5] into bank bits
// [1:0] -> 2 lanes/bank (free, m136). Involution, bijective on [0,640).
__device__ __forceinline__ int swz(int i) { return i ^ ((i >> 5) & 3); }

__global__ __launch_bounds__(512)
void fofe_kernel(const float* __restrict__ x,
                 const float* __restrict__ alpha,
                 float* __restrict__ out)
{
    __shared__ float zs[NTAU][ZROW];    // 40 KB
    __shared__ float lut[NTAU][NW];     // alpha^{w_i} per slab, 3.1 KB

    const int tid  = threadIdx.x;
    const int wid  = tid >> 6;          // 0..7
    const int lane = tid & 63;
    const int blk  = blockIdx.x;

    // ---------- phase 1: all 16 row-scans (wave w: tau = w, w+8) ----------
    for (int tau = wid; tau < NTAU; tau += 8) {
        const int g = tau * GRID + blk;
        const float al = alpha[g & (CC - 1)];
        const float* xr = x + (size_t)g * LL;

        const f32x4 xv0 = reinterpret_cast<const f32x4*>(xr)[lane * 2];
        const f32x4 xv1 = reinterpret_cast<const f32x4*>(xr)[lane * 2 + 1];
        const float xe[8] = {xv0.x, xv0.y, xv0.z, xv0.w,
                             xv1.x, xv1.y, xv1.z, xv1.w};
        float l[8];
        {
            float s = 0.f;
            #pragma unroll
            for (int m = 0; m < 8; ++m) { s = fmaf(al, s, xe[m]); l[m] = s; }
        }
        float pw[8];                    // alpha^{m+1}
        {
            float p = al;
            #pragma unroll
            for (int m = 0; m < 8; ++m) { pw[m] = p; p *= al; }
        }
        float A = pw[7], S = l[7];
        #pragma unroll
        for (int off = 1; off < 64; off <<= 1) {
            const float Ap = __shfl_up(A, off);
            const float Sp = __shfl_up(S, off);
            if (lane >= off) { S = fmaf(A, Sp, S); A = A * Ap; }
        }
        float carry = __shfl_up(S, 1);
        if (lane == 0) carry = 0.f;

        float* z = zs[tau];
        z[swz(lane)] = 0.f;             // k = 0..63
        if (lane == 0) z[swz(64)] = 0.f;// k = 64 (z[-1])
        #pragma unroll
        for (int m = 0; m < 8; ++m)
            z[swz(ZOFF + lane * 8 + m)] = fmaf(pw[m], carry, l[m]);
    }
    // alpha^w LUT (49 threads x 16 taus; one-time)
    if (tid < NW) {
        const int w = (tid < 48) ? tid : 64;
        for (int tau = 0; tau < NTAU; ++tau) {
            const int g = tau * GRID + blk;
            const float al = alpha[g & (CC - 1)];
            float p = 1.f, m = al;
            #pragma unroll
            for (int b = 0; b < 7; ++b) { if (w & (1 << b)) p *= m; m *= m; }
            lut[tau][tid] = p;
        }
    }
    __syncthreads();   // the only barrier; LDS is read-only below

    // ---------- phase 2: balanced barrier-free sweep, 98 rows per wave ------
    for (int R = wid; R < NROWS; R += 8) {
        const unsigned tau = (unsigned)R / NW;     // magic-mul divide
        const int      i   = R - (int)tau * NW;
        const int      g   = (int)tau * GRID + blk;
        const float*   z   = zs[tau];
        const int      w   = (i < 48) ? i : 64;
        const float    apw = lut[tau][i];
        float* op = out + (size_t)g * SLAB + i * LO;

        // element phase of op = (g*25137 + i*513) & 3 = (g + i) & 3
        const int peel = (4 - ((g + i) & 3)) & 3;
        const int k0b  = ZOFF - 1;                 // + t gives z[t-1]

        if (lane < peel)
            op[lane] = fmaf(-apw, z[swz(k0b + lane - w)], z[swz(k0b + lane)]);

        const int nf4  = (LO - peel) >> 2;         // 127 or 128
        const int tail = (LO - peel) & 3;
        for (int f = lane; f < nf4; f += 64) {
            const int t0 = peel + 4 * f;
            const int k0 = k0b + t0;
            f32x4 v;
            v.x = fmaf(-apw, z[swz(k0     - w)], z[swz(k0    )]);
            v.y = fmaf(-apw, z[swz(k0 + 1 - w)], z[swz(k0 + 1)]);
            v.z = fmaf(-apw, z[swz(k0 + 2 - w)], z[swz(k0 + 2)]);
            v.w = fmaf(-apw, z[swz(k0 + 3 - w)], z[swz(k0 + 3)]);
            *reinterpret_cast<f32x4*>(op + t0) = v;    // 16B-aligned
        }
        if (lane < tail) {
            const int t = peel + 4 * nf4 + lane;
            op[t] = fmaf(-apw, z[swz(k0b + t - w)], z[swz(k0b + t)]);
        }
    }
}

extern "C" void kernel_launch(void* const* d_in, const int* in_sizes, int n_in,
                              void* d_out, int out_size, void* d_ws, size_t ws_size,
                              hipStream_t stream)
{
    const float* x     = (const float*)d_in[0];
    const float* alpha = (const float*)d_in[1];
    float* out = (float*)d_out;

    fofe_kernel<<<GRID, 512, 0, stream>>>(x, alpha, out);
}

// Round 12
// 89.484 us; speedup vs baseline: 1.1958x; 1.1042x over previous
//
#include <hip/hip_runtime.h>

// FOFE windowed encoder — sweep-ordered writer, 2 blocks/CU.
// out[b,c,i,t] = z[t-1] - alpha^{w_i} * z[t-1-w_i];  z[t]=alpha*z[t-1]+x[t]
// w_i = i (i<48), w_48 = 64. out shape (8,512,49,513) f32 (~412 MB).
//
// R6 (sweep, 1 blk/CU, per-tau barrier) = 85.9 us, champion. R8/R9 proved the
// barrier is load-bearing (drop it -> waves drift -> 99-107 us). R6's residual
// vs the ~62 us HBM floor = barrier bubbles: 12.5% row imbalance idle + 16
// vmcnt(0) store-queue drains, with nothing else on the CU to run.
// ONE change: GRID 256->512, NTAU 16->8 => 2 blocks/CU. The co-resident block
// overlaps the bubbles; write window 25->51 MB (still tight).

#define CC 512
#define LL 512
#define NW 49
#define LO 513
#define SLAB (NW * LO)        // 25137 floats per (b,c)
#define GRID 512
#define NTAU 8                // 4096 slabs / 512 blocks
#define ZOFF 65               // z[q] at k = ZOFF + q; zeros for k < 65
#define ZROW 640

typedef float f32x4 __attribute__((ext_vector_type(4)));

// XOR-swizzle for stride-4 lane access: inject idx bits [6:5] into bank bits
// [1:0] -> 2 lanes/bank (free, m136). Involution, bijective on [0,640).
__device__ __forceinline__ int swz(int i) { return i ^ ((i >> 5) & 3); }

__global__ __launch_bounds__(512, 4)
void fofe_kernel(const float* __restrict__ x,
                 const float* __restrict__ alpha,
                 float* __restrict__ out)
{
    __shared__ float zs[NTAU][ZROW];   // 20 KB -> two blocks fit easily

    const int tid  = threadIdx.x;
    const int wid  = tid >> 6;         // 0..7
    const int lane = tid & 63;
    const int blk  = blockIdx.x;

    // ---------- phase 1: row-scans, one tau per wave (8 waves, 8 taus) ------
    for (int tau = wid; tau < NTAU; tau += 8) {
        const int g = tau * GRID + blk;            // global slab / row index
        const float al = alpha[g & (CC - 1)];
        const float* xr = x + (size_t)g * LL;

        const f32x4 xv0 = reinterpret_cast<const f32x4*>(xr)[lane * 2];
        const f32x4 xv1 = reinterpret_cast<const f32x4*>(xr)[lane * 2 + 1];
        const float xe[8] = {xv0.x, xv0.y, xv0.z, xv0.w,
                             xv1.x, xv1.y, xv1.z, xv1.w};
        float l[8];
        {
            float s = 0.f;
            #pragma unroll
            for (int m = 0; m < 8; ++m) { s = fmaf(al, s, xe[m]); l[m] = s; }
        }
        float pw[8];                               // alpha^{m+1}
        {
            float p = al;
            #pragma unroll
            for (int m = 0; m < 8; ++m) { pw[m] = p; p *= al; }
        }
        float A = pw[7], S = l[7];
        #pragma unroll
        for (int off = 1; off < 64; off <<= 1) {
            const float Ap = __shfl_up(A, off);
            const float Sp = __shfl_up(S, off);
            if (lane >= off) { S = fmaf(A, Sp, S); A = A * Ap; }
        }
        float carry = __shfl_up(S, 1);
        if (lane == 0) carry = 0.f;

        float* z = zs[tau];
        z[swz(lane)] = 0.f;                        // k = 0..63
        if (lane == 0) z[swz(64)] = 0.f;           // k = 64   (z[-1])
        #pragma unroll
        for (int m = 0; m < 8; ++m)
            z[swz(ZOFF + lane * 8 + m)] = fmaf(pw[m], carry, l[m]);
    }
    __syncthreads();

    // ---------- phase 2: sweep-write slabs tau = 0..7 ----------
    for (int tau = 0; tau < NTAU; ++tau) {
        const int g = tau * GRID + blk;
        const float al = alpha[g & (CC - 1)];
        const float* z = zs[tau];
        float* oslab = out + (size_t)g * SLAB;

        const float a2  = al * al, a4 = a2 * a2, a8 = a4 * a4;
        const float a16 = a8 * a8;
        const float a64 = (a16 * a16) * (a16 * a16);

        // p = alpha^wid (3-bit exponent by squaring)
        float p = 1.f;
        {
            float m = al;
            #pragma unroll
            for (int b = 0; b < 3; ++b) { if (wid & (1 << b)) p *= m; m *= m; }
        }

        // wave w writes rows i = w, w+8, ... (wave 0 also gets i=48 / w=64)
        for (int i = wid; i < NW; i += 8) {
            const int   w   = (i < 48) ? i : 64;
            const float apw = (i < 48) ? p : a64;
            float* op = oslab + i * LO;
            // element phase of op = (g + i) & 3   (25137%4==1, 513%4==1)
            const int q    = (g + i) & 3;
            const int peel = (4 - q) & 3;
            const int k0b  = ZOFF - 1;             // + t gives z[t-1]

            if (lane < peel)
                op[lane] = fmaf(-apw, z[swz(k0b + lane - w)], z[swz(k0b + lane)]);

            const int nf4  = (LO - peel) >> 2;
            const int tail = (LO - peel) & 3;
            for (int f = lane; f < nf4; f += 64) {
                const int t0 = peel + 4 * f;
                const int k0 = k0b + t0;
                f32x4 v;
                v.x = fmaf(-apw, z[swz(k0     - w)], z[swz(k0    )]);
                v.y = fmaf(-apw, z[swz(k0 + 1 - w)], z[swz(k0 + 1)]);
                v.z = fmaf(-apw, z[swz(k0 + 2 - w)], z[swz(k0 + 2)]);
                v.w = fmaf(-apw, z[swz(k0 + 3 - w)], z[swz(k0 + 3)]);
                *reinterpret_cast<f32x4*>(op + t0) = v;    // 16B-aligned
            }
            if (lane < tail) {
                const int t = peel + 4 * nf4 + lane;
                op[t] = fmaf(-apw, z[swz(k0b + t - w)], z[swz(k0b + t)]);
            }
            p *= a8;
        }
        __syncthreads();   // keep the block's waves in the same slab window
    }
}

extern "C" void kernel_launch(void* const* d_in, const int* in_sizes, int n_in,
                              void* d_out, int out_size, void* d_ws, size_t ws_size,
                              hipStream_t stream)
{
    const float* x     = (const float*)d_in[0];
    const float* alpha = (const float*)d_in[1];
    float* out = (float*)d_out;

    fofe_kernel<<<GRID, 512, 0, stream>>>(x, alpha, out);
}

// Round 13
// 85.515 us; speedup vs baseline: 1.2513x; 1.0464x over previous
//
#include <hip/hip_runtime.h>

// FOFE windowed encoder — sweep-ordered, balanced, drain-free pacing.
// out[b,c,i,t] = z[t-1] - alpha^{w_i} * z[t-1-w_i];  z[t]=alpha*z[t-1]+x[t]
// w_i = i (i<48), w_48 = 64. out shape (8,512,49,513) f32 (~412 MB).
//
// R6 (sweep, 1 blk/CU, per-tau __syncthreads, 7-vs-6 rows) = 85.9 us.
// R8/R9: no barrier -> drift -> slower. R11: 2 blk/CU -> window widens -> slower.
// This round, ONLY the two R6 bubbles, same structure:
//   1. perfect balance: each wave 6 full rows (i = wid+8k, k<6); row 48 split
//      8 ways as 64 scalar elems/wave (t = wid*64+lane; tid 511 takes t=512).
//   2. phase-2 barriers are pure pacing (LDS read-only, stores independent):
//      raw s_barrier, NO vmcnt(0) store-queue drain (__syncthreads would).

#define CC 512
#define LL 512
#define NW 49
#define LO 513
#define SLAB (NW * LO)        // 25137 floats per (b,c)
#define GRID 256
#define NTAU 16               // 4096 slabs / 256 blocks
#define ZOFF 65               // z[q] at k = ZOFF + q; zeros for k < 65
#define ZROW 640

typedef float f32x4 __attribute__((ext_vector_type(4)));

// XOR-swizzle for stride-4 lane access: inject idx bits [6:5] into bank bits
// [1:0] -> 2 lanes/bank (free, m136). Involution, bijective on [0,640).
__device__ __forceinline__ int swz(int i) { return i ^ ((i >> 5) & 3); }

__global__ __launch_bounds__(512)
void fofe_kernel(const float* __restrict__ x,
                 const float* __restrict__ alpha,
                 float* __restrict__ out)
{
    __shared__ float zs[NTAU][ZROW];   // 40 KB

    const int tid  = threadIdx.x;
    const int wid  = tid >> 6;         // 0..7
    const int lane = tid & 63;
    const int blk  = blockIdx.x;

    // ---------- phase 1: all 16 row-scans (wave w: tau = w, w+8) ----------
    for (int tau = wid; tau < NTAU; tau += 8) {
        const int g = tau * GRID + blk;            // global slab / row index
        const float al = alpha[g & (CC - 1)];
        const float* xr = x + (size_t)g * LL;

        const f32x4 xv0 = reinterpret_cast<const f32x4*>(xr)[lane * 2];
        const f32x4 xv1 = reinterpret_cast<const f32x4*>(xr)[lane * 2 + 1];
        const float xe[8] = {xv0.x, xv0.y, xv0.z, xv0.w,
                             xv1.x, xv1.y, xv1.z, xv1.w};
        float l[8];
        {
            float s = 0.f;
            #pragma unroll
            for (int m = 0; m < 8; ++m) { s = fmaf(al, s, xe[m]); l[m] = s; }
        }
        float pw[8];                               // alpha^{m+1}
        {
            float p = al;
            #pragma unroll
            for (int m = 0; m < 8; ++m) { pw[m] = p; p *= al; }
        }
        float A = pw[7], S = l[7];
        #pragma unroll
        for (int off = 1; off < 64; off <<= 1) {
            const float Ap = __shfl_up(A, off);
            const float Sp = __shfl_up(S, off);
            if (lane >= off) { S = fmaf(A, Sp, S); A = A * Ap; }
        }
        float carry = __shfl_up(S, 1);
        if (lane == 0) carry = 0.f;

        float* z = zs[tau];
        z[swz(lane)] = 0.f;                        // k = 0..63
        if (lane == 0) z[swz(64)] = 0.f;           // k = 64   (z[-1])
        #pragma unroll
        for (int m = 0; m < 8; ++m)
            z[swz(ZOFF + lane * 8 + m)] = fmaf(pw[m], carry, l[m]);
    }
    __syncthreads();   // the one real barrier: LDS writes -> visible to all

    // ---------- phase 2: sweep-write slabs tau = 0..15, balanced ----------
    for (int tau = 0; tau < NTAU; ++tau) {
        const int g = tau * GRID + blk;
        const float al = alpha[g & (CC - 1)];
        const float* z = zs[tau];
        float* oslab = out + (size_t)g * SLAB;

        const float a2  = al * al, a4 = a2 * a2, a8 = a4 * a4;
        const float a16 = a8 * a8;
        const float a64 = (a16 * a16) * (a16 * a16);
        const int   k0b = ZOFF - 1;                // + t gives z[t-1]

        // p = alpha^wid (3-bit exponent by squaring)
        float p = 1.f;
        {
            float m = al;
            #pragma unroll
            for (int b = 0; b < 3; ++b) { if (wid & (1 << b)) p *= m; m *= m; }
        }

        // exactly 6 full rows per wave: i = wid, wid+8, ..., wid+40
        #pragma unroll
        for (int k = 0; k < 6; ++k) {
            const int   i   = wid + 8 * k;
            const int   w   = i;
            const float apw = p;
            float* op = oslab + i * LO;
            // element phase of op = (g + i) & 3   (25137%4==1, 513%4==1)
            const int peel = (4 - ((g + i) & 3)) & 3;

            if (lane < peel)
                op[lane] = fmaf(-apw, z[swz(k0b + lane - w)], z[swz(k0b + lane)]);

            const int nf4  = (LO - peel) >> 2;
            const int tail = (LO - peel) & 3;
            for (int f = lane; f < nf4; f += 64) {
                const int t0 = peel + 4 * f;
                const int k0 = k0b + t0;
                f32x4 v;
                v.x = fmaf(-apw, z[swz(k0     - w)], z[swz(k0    )]);
                v.y = fmaf(-apw, z[swz(k0 + 1 - w)], z[swz(k0 + 1)]);
                v.z = fmaf(-apw, z[swz(k0 + 2 - w)], z[swz(k0 + 2)]);
                v.w = fmaf(-apw, z[swz(k0 + 3 - w)], z[swz(k0 + 3)]);
                *reinterpret_cast<f32x4*>(op + t0) = v;    // 16B-aligned
            }
            if (lane < tail) {
                const int t = peel + 4 * nf4 + lane;
                op[t] = fmaf(-apw, z[swz(k0b + t - w)], z[swz(k0b + t)]);
            }
            p *= a8;
        }

        // row 48 (w = 64): split 8 ways, one scalar elem per lane
        {
            float* op = oslab + 48 * LO;
            const int t = wid * 64 + lane;         // 0..511
            op[t] = fmaf(-a64, z[swz(k0b + t - 64)], z[swz(k0b + t)]);
            if (tid == 511)
                op[512] = fmaf(-a64, z[swz(k0b + 512 - 64)], z[swz(k0b + 512)]);
        }

        // pacing barrier only — no memory dependence, so no waitcnt drain
        __builtin_amdgcn_s_barrier();
    }
}

extern "C" void kernel_launch(void* const* d_in, const int* in_sizes, int n_in,
                              void* d_out, int out_size, void* d_ws, size_t ws_size,
                              hipStream_t stream)
{
    const float* x     = (const float*)d_in[0];
    const float* alpha = (const float*)d_in[1];
    float* out = (float*)d_out;

    fofe_kernel<<<GRID, 512, 0, stream>>>(x, alpha, out);
}